// Round 10
// baseline (90.351 us; speedup 1.0000x reference)
//
#include <hip/hip_runtime.h>
#include <hip/hip_bf16.h>

// Problem constants (from setup_inputs): B=8, N=M=4096, 3D points, fp32.
constexpr int B_ = 8;
constexpr int N_ = 4096;
constexpr int M_ = 4096;
constexpr int TPB1 = 1024;          // 16 waves/block
constexpr int QPB = 256;            // queries per block
constexpr int QUARTER = M_ / 4;     // 1024 db points per wave-quarter
constexpr int NTILE = QUARTER / 16; // 64 B-tiles of 16 points per quarter
constexpr int NBLK = 2 * B_ * (N_ / QPB);   // 256 blocks = 1/CU

typedef _Float16 half8 __attribute__((ext_vector_type(8)));
typedef float    f32x4 __attribute__((ext_vector_type(4)));

// ---------------------------------------------------------------------------
// Single fused kernel: chamfer (MFMA rank-4 embedding) + last-block finalize.
//   d^2 = min_p(||p||^2 - 2 q.p) + ||q||^2
//   A row q = {qx,qy,qz,1,0...}, B col p = {-2px,-2py,-2pz,||p||^2,0...}
//   mfma_f32_16x16x32_f16 -> acc[q][p] = ||p||^2 - 2 q.p  (f32 accum).
// Block = (dir, batch, q-chunk of 256); full 4096-pt db in 64 KB LDS;
// 16 waves = query-group (w>>2) x db-quarter (w&3); 256 blocks = 1/CU.
// Cross-block: block partial -> part[bid]; __threadfence + atomicAdd on a
// zero-initialized counter; the 256th block re-fences, tree-sums the 256
// partials in FIXED order (bit-deterministic regardless of which block is
// last) and adds the registration loss, writing out[0..2] directly.
// C/D layout (HW-verified): col=lane&15, row=(lane>>4)*4+reg.
// ---------------------------------------------------------------------------
__global__ __launch_bounds__(TPB1) void chamfer_all(
    const float* __restrict__ X, const float* __restrict__ Yp,
    const float* __restrict__ R,  const float* __restrict__ t,
    const float* __restrict__ S,  const float* __restrict__ Rg,
    const float* __restrict__ tg, const float* __restrict__ Sg,
    float* __restrict__ part, int* __restrict__ counter,
    float* __restrict__ out)
{
    __shared__ half8 sB[M_ + 1];        // 64 KB + 16 B zero slot
    __shared__ float smin[4 * QPB];     // 4 KB
    __shared__ float wsum16[16];
    __shared__ float sreg[8];
    __shared__ int   sflag;

    int bid = blockIdx.x;
    const int dir    = bid & 1;   bid >>= 1;
    const int qchunk = bid & 15;  bid >>= 4;
    const int b      = bid;       // 0..7

    const float* q  = dir ? Yp : X;
    const float* db = dir ? X  : Yp;

    const int tid  = threadIdx.x;
    const int lane = tid & 63;
    const int wave = tid >> 6;          // 0..15
    const int quarter = wave & 3;       // db quarter
    const int qgroup  = wave >> 2;      // query group of 64
    const int l15  = lane & 15;

    // ---- Stage the full db for this batch: 4 points/thread via 3x float4.
    {
        const float4* src4 = (const float4*)(db + (size_t)b * M_ * 3);
        float4 f0 = src4[tid * 3 + 0];
        float4 f1 = src4[tid * 3 + 1];
        float4 f2 = src4[tid * 3 + 2];
        float px[4] = {f0.x, f0.w, f1.z, f2.y};
        float py[4] = {f0.y, f1.x, f1.w, f2.z};
        float pz[4] = {f0.z, f1.y, f2.x, f2.w};
        #pragma unroll
        for (int i = 0; i < 4; ++i) {
            float pn = px[i] * px[i] + py[i] * py[i] + pz[i] * pz[i];
            half8 v;
            v[0] = (_Float16)(-2.0f * px[i]);
            v[1] = (_Float16)(-2.0f * py[i]);
            v[2] = (_Float16)(-2.0f * pz[i]);
            v[3] = (_Float16)pn;
            v[4] = (_Float16)0.0f; v[5] = (_Float16)0.0f;
            v[6] = (_Float16)0.0f; v[7] = (_Float16)0.0f;
            sB[tid * 4 + i] = v;
        }
    }
    if (tid == 0) {
        half8 z;
        #pragma unroll
        for (int i = 0; i < 8; ++i) z[i] = (_Float16)0.0f;
        sB[M_] = z;
    }

    // ---- Build 4 A fragments (this wave's 64 queries) in registers.
    const int qglob = b * N_ + qchunk * QPB + qgroup * 64;
    half8 af[4];
    #pragma unroll
    for (int f = 0; f < 4; ++f) {
        half8 v;
        #pragma unroll
        for (int i = 0; i < 8; ++i) v[i] = (_Float16)0.0f;
        if (lane < 16) {
            const float* qp = q + (size_t)(qglob + f * 16 + l15) * 3;
            v[0] = (_Float16)qp[0];
            v[1] = (_Float16)qp[1];
            v[2] = (_Float16)qp[2];
            v[3] = (_Float16)1.0f;
        }
        af[f] = v;
    }
    __syncthreads();

    // ---- Inner loop over this wave's quarter: 1 ds_read_b128 -> 4 MFMAs.
    const half8* bp = sB + ((lane < 16) ? (quarter * QUARTER + l15) : M_);
    const int step  = (lane < 16) ? 16 : 0;

    f32x4 zero4; zero4[0] = 0.f; zero4[1] = 0.f; zero4[2] = 0.f; zero4[3] = 0.f;
    const float BIG = 3.0e38f;
    float rm[4][4];
    #pragma unroll
    for (int f = 0; f < 4; ++f)
        #pragma unroll
        for (int i = 0; i < 4; ++i) rm[f][i] = BIG;

    for (int tt = 0; tt < NTILE; tt += 2) {
        half8 b0 = bp[0];
        half8 b1 = bp[step];
        bp += (step << 1);
        f32x4 a0[4], a1[4];
        #pragma unroll
        for (int f = 0; f < 4; ++f)
            a0[f] = __builtin_amdgcn_mfma_f32_16x16x32_f16(af[f], b0, zero4, 0, 0, 0);
        #pragma unroll
        for (int f = 0; f < 4; ++f)
            a1[f] = __builtin_amdgcn_mfma_f32_16x16x32_f16(af[f], b1, zero4, 0, 0, 0);
        #pragma unroll
        for (int f = 0; f < 4; ++f)
            #pragma unroll
            for (int i = 0; i < 4; ++i)
                rm[f][i] = fminf(rm[f][i], fminf(a0[f][i], a1[f][i]));  // v_min3
    }

    // ---- Min over the 16 db columns (lanes differing in bits 0..3).
    #pragma unroll
    for (int f = 0; f < 4; ++f)
        #pragma unroll
        for (int i = 0; i < 4; ++i) {
            float v = rm[f][i];
            v = fminf(v, __shfl_xor(v, 1, 64));
            v = fminf(v, __shfl_xor(v, 2, 64));
            v = fminf(v, __shfl_xor(v, 4, 64));
            v = fminf(v, __shfl_xor(v, 8, 64));
            rm[f][i] = v;
        }

    // ---- Each lane emits one query: j = f_sel*16 + (lane>>4)*4 + i_sel
    // (bijective over 64 lanes). Static-index extraction via cndmask.
    const int f_sel = (lane >> 2) & 3;
    const int i_sel = lane & 3;
    float v = BIG;
    #pragma unroll
    for (int f = 0; f < 4; ++f)
        #pragma unroll
        for (int i = 0; i < 4; ++i)
            if (f == f_sel && i == i_sel) v = rm[f][i];

    const int j = f_sel * 16 + ((lane >> 4) << 2) + i_sel;
    smin[quarter * QPB + qgroup * 64 + j] = v;
    __syncthreads();

    // ---- Final per-query min across quarters, + ||q||^2, sqrt, block sum.
    float d = 0.0f;
    if (tid < QPB) {
        float m = fminf(fminf(smin[tid], smin[QPB + tid]),
                        fminf(smin[2 * QPB + tid], smin[3 * QPB + tid]));
        const float* qp = q + (size_t)(b * N_ + qchunk * QPB + tid) * 3;
        const float qn = qp[0] * qp[0] + qp[1] * qp[1] + qp[2] * qp[2];
        d = sqrtf(fmaxf(m + qn, 0.0f));
    }
    #pragma unroll
    for (int off = 32; off > 0; off >>= 1) d += __shfl_down(d, off, 64);
    if (lane == 0) wsum16[wave] = d;
    __syncthreads();

    // ---- Publish block partial; the 256th block to finish finalizes.
    if (tid == 0) {
        float s = 0.0f;
        #pragma unroll
        for (int w = 0; w < 16; ++w) s += wsum16[w];
        part[blockIdx.x] = s;
        __threadfence();                       // release partials
        int old = atomicAdd(counter, 1);       // device-scope
        sflag = (old == NBLK - 1) ? 1 : 0;
    }
    __syncthreads();

    if (sflag) {
        __threadfence();                       // acquire all partials
        // Registration loss (8 batches on threads 0..7).
        if (tid < 8) {
            const float* Rb  = R  + tid * 9;
            const float* Rgb = Rg + tid * 9;
            float acc = 0.0f;
            #pragma unroll
            for (int i = 0; i < 3; ++i) {
                #pragma unroll
                for (int k = 0; k < 3; ++k) {
                    float vv = 0.0f;
                    #pragma unroll
                    for (int jj = 0; jj < 3; ++jj)
                        vv = fmaf(Rgb[jj * 3 + i], Rb[jj * 3 + k], vv);  // (R_g^T R)[i][k]
                    if (i == k) vv -= 1.0f;
                    acc = fmaf(vv, vv, acc);
                }
            }
            #pragma unroll
            for (int dd = 0; dd < 3; ++dd) {
                float dv = tg[tid * 3 + dd] - t[tid * 3 + dd];
                acc = fmaf(dv, dv, acc);
            }
            float dS = Sg[tid] - S[tid];
            acc = fmaf(dS, dS, acc);
            sreg[tid] = acc;
        }
        // Fixed-order tree sum of the 256 partials (deterministic).
        float s = (tid < NBLK) ? ((volatile float*)part)[tid] : 0.0f;
        #pragma unroll
        for (int off = 32; off > 0; off >>= 1) s += __shfl_down(s, off, 64);
        if (lane == 0) wsum16[wave] = s;
        __syncthreads();
        if (tid == 0) {
            float tot = 0.0f;
            #pragma unroll
            for (int w = 0; w < 16; ++w) tot += wsum16[w];
            float L_CD = tot / (float)(B_ * N_);   // sum/(B*N)+sum/(B*M), N==M
            float rs = 0.0f;
            #pragma unroll
            for (int bb = 0; bb < 8; ++bb) rs += sreg[bb];
            float L_R = rs / (float)B_;
            out[0] = L_R + L_CD;
            out[1] = L_R;
            out[2] = L_CD;
        }
    }
}

extern "C" void kernel_launch(void* const* d_in, const int* in_sizes, int n_in,
                              void* d_out, int out_size, void* d_ws, size_t ws_size,
                              hipStream_t stream) {
    const float* R  = (const float*)d_in[0];
    const float* t  = (const float*)d_in[1];
    const float* S  = (const float*)d_in[2];
    const float* Rg = (const float*)d_in[3];
    const float* tg = (const float*)d_in[4];
    const float* Sg = (const float*)d_in[5];
    const float* X  = (const float*)d_in[6];   // T_X [B,N,3]
    const float* Yp = (const float*)d_in[7];   // Y   [B,M,3]
    float* out = (float*)d_out;

    float* part   = (float*)d_ws;              // NBLK floats
    int* counter  = (int*)(part + NBLK);       // 1 int, zeroed below

    hipMemsetAsync(counter, 0, sizeof(int), stream);
    chamfer_all<<<NBLK, TPB1, 0, stream>>>(X, Yp, R, t, S, Rg, tg, Sg,
                                           part, counter, out);
}

// Round 11
// 82.507 us; speedup vs baseline: 1.0951x; 1.0951x over previous
//
#include <hip/hip_runtime.h>
#include <hip/hip_bf16.h>

// Problem constants (from setup_inputs): B=8, N=M=4096, 3D points, fp32.
constexpr int B_ = 8;
constexpr int N_ = 4096;
constexpr int M_ = 4096;
constexpr int TPB1 = 1024;          // 16 waves/block (fused pass)
constexpr int QPB = 256;            // queries per block
constexpr int QUARTER = M_ / 4;     // 1024 db points per wave-quarter
constexpr int NTILE = QUARTER / 16; // 64 B-tiles of 16 points per quarter
constexpr int NBLK = 2 * B_ * (N_ / QPB);   // 256 blocks = 1/CU

typedef _Float16 half8 __attribute__((ext_vector_type(8)));
typedef float    f32x4 __attribute__((ext_vector_type(4)));

// ---------------------------------------------------------------------------
// Fused chamfer: block = (dir, batch, q-chunk of 256). ONE kernel computes
// final per-query min over the whole db -> sqrt -> block partial sum.
// d^2 = min_p(||p||^2 - 2 q.p) + ||q||^2 as a rank-4 f16 GEMM:
//   A row q = {qx,qy,qz,1,0...}, B col p = {-2px,-2py,-2pz,||p||^2,0...}
//   mfma_f32_16x16x32_f16 -> acc[q][p] = ||p||^2 - 2 q.p  (f32 accum).
// Full 4096-pt db staged once in 64 KB LDS. 16 waves: wave w = query-group
// (w>>2, 64 queries) x db-quarter (w&3, 1024 pts). 256 blocks = 1 block/CU,
// 4 waves/SIMD. Cross-wave min via smin[4][256] + barrier; no cross-block
// combining, no atomics, no ws init. Block writes one partial.
// C/D layout (HW-verified): col=lane&15, row=(lane>>4)*4+reg.
// ---------------------------------------------------------------------------
__global__ __launch_bounds__(TPB1) void chamfer_fused(
    const float* __restrict__ X, const float* __restrict__ Yp,
    float* __restrict__ part)
{
    __shared__ half8 sB[M_ + 1];        // 64 KB + 16 B zero slot
    __shared__ float smin[4 * QPB];     // 4 KB
    __shared__ float wsum16[16];

    int bid = blockIdx.x;
    const int dir    = bid & 1;   bid >>= 1;
    const int qchunk = bid & 15;  bid >>= 4;
    const int b      = bid;       // 0..7

    const float* q  = dir ? Yp : X;
    const float* db = dir ? X  : Yp;

    const int tid  = threadIdx.x;
    const int lane = tid & 63;
    const int wave = tid >> 6;          // 0..15
    const int quarter = wave & 3;       // db quarter
    const int qgroup  = wave >> 2;      // query group of 64
    const int l15  = lane & 15;

    // ---- Stage the full db for this batch (4 points/thread).
    const int dbbase = b * M_;
    #pragma unroll
    for (int k = 0; k < M_ / TPB1; ++k) {
        const int pt = tid + k * TPB1;
        const float* pp = db + (size_t)(dbbase + pt) * 3;
        float px = pp[0], py = pp[1], pz = pp[2];
        float pn = px * px + py * py + pz * pz;
        half8 v;
        v[0] = (_Float16)(-2.0f * px);
        v[1] = (_Float16)(-2.0f * py);
        v[2] = (_Float16)(-2.0f * pz);
        v[3] = (_Float16)pn;
        v[4] = (_Float16)0.0f; v[5] = (_Float16)0.0f;
        v[6] = (_Float16)0.0f; v[7] = (_Float16)0.0f;
        sB[pt] = v;
    }
    if (tid == 0) {
        half8 z;
        #pragma unroll
        for (int i = 0; i < 8; ++i) z[i] = (_Float16)0.0f;
        sB[M_] = z;
    }

    // ---- Build 4 A fragments (this wave's 64 queries) in registers.
    const int qglob = b * N_ + qchunk * QPB + qgroup * 64;
    half8 af[4];
    #pragma unroll
    for (int f = 0; f < 4; ++f) {
        half8 v;
        #pragma unroll
        for (int i = 0; i < 8; ++i) v[i] = (_Float16)0.0f;
        if (lane < 16) {
            const float* qp = q + (size_t)(qglob + f * 16 + l15) * 3;
            v[0] = (_Float16)qp[0];
            v[1] = (_Float16)qp[1];
            v[2] = (_Float16)qp[2];
            v[3] = (_Float16)1.0f;
        }
        af[f] = v;
    }
    __syncthreads();

    // ---- Inner loop over this wave's quarter: 1 ds_read_b128 -> 4 MFMAs.
    const half8* bp = sB + ((lane < 16) ? (quarter * QUARTER + l15) : M_);
    const int step  = (lane < 16) ? 16 : 0;

    f32x4 zero4; zero4[0] = 0.f; zero4[1] = 0.f; zero4[2] = 0.f; zero4[3] = 0.f;
    const float BIG = 3.0e38f;
    float rm[4][4];
    #pragma unroll
    for (int f = 0; f < 4; ++f)
        #pragma unroll
        for (int i = 0; i < 4; ++i) rm[f][i] = BIG;

    for (int t = 0; t < NTILE; t += 2) {
        half8 b0 = bp[0];
        half8 b1 = bp[step];
        bp += (step << 1);
        f32x4 a0[4], a1[4];
        #pragma unroll
        for (int f = 0; f < 4; ++f)
            a0[f] = __builtin_amdgcn_mfma_f32_16x16x32_f16(af[f], b0, zero4, 0, 0, 0);
        #pragma unroll
        for (int f = 0; f < 4; ++f)
            a1[f] = __builtin_amdgcn_mfma_f32_16x16x32_f16(af[f], b1, zero4, 0, 0, 0);
        #pragma unroll
        for (int f = 0; f < 4; ++f)
            #pragma unroll
            for (int i = 0; i < 4; ++i)
                rm[f][i] = fminf(rm[f][i], fminf(a0[f][i], a1[f][i]));  // v_min3
    }

    // ---- Min over the 16 db columns (lanes differing in bits 0..3).
    #pragma unroll
    for (int f = 0; f < 4; ++f)
        #pragma unroll
        for (int i = 0; i < 4; ++i) {
            float v = rm[f][i];
            v = fminf(v, __shfl_xor(v, 1, 64));
            v = fminf(v, __shfl_xor(v, 2, 64));
            v = fminf(v, __shfl_xor(v, 4, 64));
            v = fminf(v, __shfl_xor(v, 8, 64));
            rm[f][i] = v;
        }

    // ---- Each lane emits one query: j = f_sel*16 + (lane>>4)*4 + i_sel
    // (bijective over 64 lanes). Static-index extraction via cndmask.
    const int f_sel = (lane >> 2) & 3;
    const int i_sel = lane & 3;
    float v = BIG;
    #pragma unroll
    for (int f = 0; f < 4; ++f)
        #pragma unroll
        for (int i = 0; i < 4; ++i)
            if (f == f_sel && i == i_sel) v = rm[f][i];

    const int j = f_sel * 16 + ((lane >> 4) << 2) + i_sel;
    smin[quarter * QPB + qgroup * 64 + j] = v;
    __syncthreads();

    // ---- Final per-query min across quarters, + ||q||^2, sqrt, block sum.
    float d = 0.0f;
    if (tid < QPB) {
        float m = fminf(fminf(smin[tid], smin[QPB + tid]),
                        fminf(smin[2 * QPB + tid], smin[3 * QPB + tid]));
        const float* qp = q + (size_t)(b * N_ + qchunk * QPB + tid) * 3;
        const float qn = qp[0] * qp[0] + qp[1] * qp[1] + qp[2] * qp[2];
        d = sqrtf(fmaxf(m + qn, 0.0f));
    }
    #pragma unroll
    for (int off = 32; off > 0; off >>= 1) d += __shfl_down(d, off, 64);
    if (lane == 0) wsum16[wave] = d;
    __syncthreads();
    if (tid == 0) {
        float s = 0.0f;
        #pragma unroll
        for (int w = 0; w < 16; ++w) s += wsum16[w];
        part[blockIdx.x] = s;
    }
}

// ---------------------------------------------------------------------------
// Finalize: 1 block x 256. Sum the 256 block partials (deterministic),
// registration loss on threads 0..7, write (total, L_R, L_CD) directly.
// ---------------------------------------------------------------------------
__global__ __launch_bounds__(256) void final_kernel(
    const float* __restrict__ part,
    const float* __restrict__ R,  const float* __restrict__ t,
    const float* __restrict__ S,  const float* __restrict__ Rg,
    const float* __restrict__ tg, const float* __restrict__ Sg,
    float* __restrict__ out)
{
    __shared__ float wsum[4];
    __shared__ float sreg[8];
    const int tid = threadIdx.x;

    float s = part[tid];
    #pragma unroll
    for (int off = 32; off > 0; off >>= 1) s += __shfl_down(s, off, 64);
    if ((tid & 63) == 0) wsum[tid >> 6] = s;

    if (tid < 8) {
        const float* Rb  = R  + tid * 9;
        const float* Rgb = Rg + tid * 9;
        float acc = 0.0f;
        #pragma unroll
        for (int i = 0; i < 3; ++i) {
            #pragma unroll
            for (int k = 0; k < 3; ++k) {
                float v = 0.0f;
                #pragma unroll
                for (int jj = 0; jj < 3; ++jj)
                    v = fmaf(Rgb[jj * 3 + i], Rb[jj * 3 + k], v);  // (R_g^T R)[i][k]
                if (i == k) v -= 1.0f;
                acc = fmaf(v, v, acc);
            }
        }
        #pragma unroll
        for (int dd = 0; dd < 3; ++dd) {
            float dv = tg[tid * 3 + dd] - t[tid * 3 + dd];
            acc = fmaf(dv, dv, acc);
        }
        float dS = Sg[tid] - S[tid];
        acc = fmaf(dS, dS, acc);
        sreg[tid] = acc;
    }
    __syncthreads();

    if (tid == 0) {
        float tot = wsum[0] + wsum[1] + wsum[2] + wsum[3];
        float L_CD = tot / (float)(B_ * N_);   // sum/(B*N) + sum/(B*M), N==M
        float rs = 0.0f;
        #pragma unroll
        for (int bb = 0; bb < 8; ++bb) rs += sreg[bb];
        float L_R = rs / (float)B_;
        out[0] = L_R + L_CD;
        out[1] = L_R;
        out[2] = L_CD;
    }
}

extern "C" void kernel_launch(void* const* d_in, const int* in_sizes, int n_in,
                              void* d_out, int out_size, void* d_ws, size_t ws_size,
                              hipStream_t stream) {
    const float* R  = (const float*)d_in[0];
    const float* t  = (const float*)d_in[1];
    const float* S  = (const float*)d_in[2];
    const float* Rg = (const float*)d_in[3];
    const float* tg = (const float*)d_in[4];
    const float* Sg = (const float*)d_in[5];
    const float* X  = (const float*)d_in[6];   // T_X [B,N,3]
    const float* Yp = (const float*)d_in[7];   // Y   [B,M,3]
    float* out = (float*)d_out;

    float* part = (float*)d_ws;                // 256 floats, fully overwritten

    chamfer_fused<<<NBLK, TPB1, 0, stream>>>(X, Yp, part);
    final_kernel<<<1, 256, 0, stream>>>(part, R, t, S, Rg, tg, Sg, out);
}